// Round 8
// baseline (214.524 us; speedup 1.0000x reference)
//
#include <hip/hip_runtime.h>

#define LAMBDA_COORD 5.0f
#define LAMBDA_NOOBJ 0.5f

// 802816 cells; preds 30 f32/cell, targets 25 f32/cell.
// R8: all rounds R3-R7 executed the same ~735 VMEM instr/CU in the same
// ~163K cycles (~220 cyc/instr => only ~4 loads in flight per CU). Root
// cause: default occupancy-targeted register allocation (VGPR 32-60) forces
// shallow load convoys; R4's launch_bounds(512,8) lowered the cap further.
// Fix: 4 cells/thread, depth-2 software-pipeline rotation, launch_bounds
// (256,2) -> VGPR cap 256 so all 15 next-cell loads stay hoisted above
// current-cell compute (steady-state 15 outstanding dwordx4 per wave).

typedef float f4u __attribute__((ext_vector_type(4), aligned(4)));
typedef float f2u __attribute__((ext_vector_type(2), aligned(4)));

struct Cell {
    f4u P0, P1, P2, P3, P4, P5, P6; f2u P7;
    f4u T0, T1, T2, T3, T4, T5; float t24;
};

__device__ __forceinline__ Cell load_cell(const float* __restrict__ p,
                                          const float* __restrict__ t) {
    Cell c;
    const f4u* p4 = (const f4u*)p;
    const f4u* t4 = (const f4u*)t;
    c.P0 = p4[0]; c.P1 = p4[1]; c.P2 = p4[2]; c.P3 = p4[3];
    c.P4 = p4[4]; c.P5 = p4[5]; c.P6 = p4[6];
    c.P7 = *(const f2u*)(p + 28);
    c.T0 = t4[0]; c.T1 = t4[1]; c.T2 = t4[2]; c.T3 = t4[3];
    c.T4 = t4[4]; c.T5 = t4[5];
    c.t24 = t[24];
    return c;
}

__device__ __forceinline__ float cell_loss(const Cell& c) {
    float p0 = c.P0.x, p5c = c.P1.y;
    // jnp.argmax picks first index on tie -> box1 only on strict greater.
    bool pick1 = p5c > p0;
    float b0 = pick1 ? p5c    : p0;
    float b1 = pick1 ? c.P1.z : c.P0.y;   // p[6] : p[1]
    float b2 = pick1 ? c.P1.w : c.P0.z;   // p[7] : p[2]
    float b3 = pick1 ? c.P2.x : c.P0.w;   // p[8] : p[3]
    float b4 = pick1 ? c.P2.y : c.P1.x;   // p[9] : p[4]

    float t0 = c.T0.x;
    float d1 = b1 - c.T0.y, d2 = b2 - c.T0.z, d3 = b3 - c.T0.w, d4 = b4 - c.T1.x;
    float box_loss = d1 * d1 + d2 * d2 + d3 * d3 + d4 * d4;
    float dpc = b0 - t0;
    float pc_loss = dpc * dpc;

    float cl = 0.0f, d;
    d = c.P2.z - c.T1.y; cl += d * d;
    d = c.P2.w - c.T1.z; cl += d * d;
    d = c.P3.x - c.T1.w; cl += d * d;
    d = c.P3.y - c.T2.x; cl += d * d;
    d = c.P3.z - c.T2.y; cl += d * d;
    d = c.P3.w - c.T2.z; cl += d * d;
    d = c.P4.x - c.T2.w; cl += d * d;
    d = c.P4.y - c.T3.x; cl += d * d;
    d = c.P4.z - c.T3.y; cl += d * d;
    d = c.P4.w - c.T3.z; cl += d * d;
    d = c.P5.x - c.T3.w; cl += d * d;
    d = c.P5.y - c.T4.x; cl += d * d;
    d = c.P5.z - c.T4.y; cl += d * d;
    d = c.P5.w - c.T4.z; cl += d * d;
    d = c.P6.x - c.T4.w; cl += d * d;
    d = c.P6.y - c.T5.x; cl += d * d;
    d = c.P6.z - c.T5.y; cl += d * d;
    d = c.P6.w - c.T5.z; cl += d * d;
    d = c.P7.x - c.T5.w; cl += d * d;
    d = c.P7.y - c.t24;  cl += d * d;

    float obj_term = LAMBDA_COORD * box_loss + pc_loss + cl;
    float noobj_term = LAMBDA_NOOBJ * (p0 * p0 + p5c * p5c);
    return (t0 == 1.0f) ? obj_term : noobj_term;
}

__global__ void zero_out_kernel(float* out, int n) {
    int i = blockIdx.x * blockDim.x + threadIdx.x;
    if (i < n) out[i] = 0.0f;
}

__global__ __launch_bounds__(256, 2) void yolo_loss_kernel(
    const float* __restrict__ preds, const float* __restrict__ targets,
    float* __restrict__ out, int n_cells)
{
    __shared__ float s_part[4];
    const int tid = threadIdx.x;
    const int q = n_cells >> 2;              // 200704 cells per quarter
    const int c = blockIdx.x * 256 + tid;    // < q by grid construction

    float acc = 0.0f;
    if (c < q) {
        // software pipeline: while computing cell i, cell i+1's 15 loads
        // are already issued (cross-iteration rotation -> structural).
        Cell A = load_cell(preds + (size_t)c * 30, targets + (size_t)c * 25);
        #pragma unroll
        for (int i = 1; i < 4; ++i) {
            const size_t cc = (size_t)(c + i * q);
            Cell B = load_cell(preds + cc * 30, targets + cc * 25);
            acc += cell_loss(A);
            A = B;
        }
        acc += cell_loss(A);
    }

    // wave (64-lane) shuffle reduction
    #pragma unroll
    for (int off = 32; off > 0; off >>= 1)
        acc += __shfl_down(acc, off, 64);

    const int wave = tid >> 6;
    if ((tid & 63) == 0) s_part[wave] = acc;
    __syncthreads();
    if (tid == 0) {
        float s = s_part[0] + s_part[1] + s_part[2] + s_part[3];
        atomicAdd(out, s);
    }
}

extern "C" void kernel_launch(void* const* d_in, const int* in_sizes, int n_in,
                              void* d_out, int out_size, void* d_ws, size_t ws_size,
                              hipStream_t stream) {
    const float* preds   = (const float*)d_in[0];
    const float* targets = (const float*)d_in[1];
    float* out = (float*)d_out;

    const int n_cells = in_sizes[0] / 30;   // 802816 = 4 * 200704

    // d_out is poisoned (0xAA) before every timed replay — zero it on-stream.
    zero_out_kernel<<<(out_size + 255) / 256, 256, 0, stream>>>(out, out_size);

    const int grid = (n_cells / 4 + 255) / 256; // 784
    yolo_loss_kernel<<<grid, 256, 0, stream>>>(preds, targets, out, n_cells);
}